// Round 12
// baseline (394.509 us; speedup 1.0000x reference)
//
#include <hip/hip_runtime.h>
#include <math.h>
#include <float.h>

constexpr int B  = 4;
constexpr int N  = 3072;
constexpr int C  = 512;
constexpr int CL = 768;

typedef unsigned short u16;
typedef __attribute__((ext_vector_type(8))) short s16x8;
typedef __attribute__((ext_vector_type(4))) float f32x4;

// ---------------- JAX threefry2x32 (exact) ----------------
__device__ __forceinline__ unsigned rotl32(unsigned v, int d) { return (v << d) | (v >> (32 - d)); }

__device__ inline void threefry2x32(unsigned k0, unsigned k1, unsigned c0, unsigned c1,
                                    unsigned& o0, unsigned& o1) {
  unsigned ks0 = k0, ks1 = k1, ks2 = 0x1BD11BDAu ^ k0 ^ k1;
  unsigned x0 = c0 + ks0, x1 = c1 + ks1;
#define TF_RND(r) { x0 += x1; x1 = rotl32(x1, (r)); x1 ^= x0; }
  TF_RND(13) TF_RND(15) TF_RND(26) TF_RND(6)  x0 += ks1; x1 += ks2 + 1u;
  TF_RND(17) TF_RND(29) TF_RND(16) TF_RND(24) x0 += ks2; x1 += ks0 + 2u;
  TF_RND(13) TF_RND(15) TF_RND(26) TF_RND(6)  x0 += ks0; x1 += ks1 + 3u;
  TF_RND(17) TF_RND(29) TF_RND(16) TF_RND(24) x0 += ks1; x1 += ks2 + 4u;
  TF_RND(13) TF_RND(15) TF_RND(26) TF_RND(6)  x0 += ks2; x1 += ks0 + 5u;
#undef TF_RND
  o0 = x0; o1 = x1;
}

__device__ inline float jax_uniform_bn(int f) {
  constexpr int HALF = (B * N) / 2;
  unsigned o0, o1, bits;
  if (f < HALF) { threefry2x32(0u, 42u, (unsigned)f, (unsigned)(f + HALF), o0, o1); bits = o0; }
  else          { threefry2x32(0u, 42u, (unsigned)(f - HALF), (unsigned)f, o0, o1); bits = o1; }
  return __uint_as_float((bits >> 9) | 0x3f800000u) - 1.0f;
}

// ---------------- bf16 split helpers ----------------
__device__ __forceinline__ u16 bf16rn(float f) {
  unsigned u = __float_as_uint(f);
  unsigned r = u + 0x7FFFu + ((u >> 16) & 1u);
  return (u16)(r >> 16);
}
__device__ __forceinline__ float bf16tof(u16 h) {
  return __uint_as_float(((unsigned)h) << 16);
}

// ---------------- prep: sq + hi/lo split + init (one wave per row) ----------------
__global__ __launch_bounds__(64) void k_prep(const float* __restrict__ x, float* __restrict__ sq,
                                             u16* __restrict__ xhi, u16* __restrict__ xlo,
                                             int* __restrict__ counts,
                                             unsigned long long* __restrict__ packed) {
  int row = blockIdx.x;   // 0..B*N-1
  int lane = threadIdx.x;
  const float* xr = x + (size_t)row * C;
  u16* hr = xhi + (size_t)row * C;
  u16* lr = xlo + (size_t)row * C;
  float s = 0.f;
  for (int c = lane * 4; c < C; c += 256) {
    float4 v = *(const float4*)(xr + c);
    s += v.x * v.x + v.y * v.y + v.z * v.z + v.w * v.w;
    u16 h0 = bf16rn(v.x), h1 = bf16rn(v.y), h2 = bf16rn(v.z), h3 = bf16rn(v.w);
    u16 l0 = bf16rn(v.x - bf16tof(h0));
    u16 l1 = bf16rn(v.y - bf16tof(h1));
    u16 l2 = bf16rn(v.z - bf16tof(h2));
    u16 l3 = bf16rn(v.w - bf16tof(h3));
    uint2 hp, lp;
    hp.x = (unsigned)h0 | ((unsigned)h1 << 16); hp.y = (unsigned)h2 | ((unsigned)h3 << 16);
    lp.x = (unsigned)l0 | ((unsigned)l1 << 16); lp.y = (unsigned)l2 | ((unsigned)l3 << 16);
    *(uint2*)(hr + c) = hp;
    *(uint2*)(lr + c) = lp;
  }
  for (int o = 32; o > 0; o >>= 1) s += __shfl_down(s, o, 64);
  if (lane == 0) {
    sq[row] = s;
    packed[row] = ~0ull;
    if (row < B * CL) counts[row] = 0;
  }
}

// ---------------- branchless sorted-insert of v into ascending t[0..4] ----------------
__device__ __forceinline__ void ins5b(float t[5], float v) {
  float c = v;
  float n;
  n = fminf(t[0], c); c = fmaxf(t[0], c); t[0] = n;
  n = fminf(t[1], c); c = fmaxf(t[1], c); t[1] = n;
  n = fminf(t[2], c); c = fmaxf(t[2], c); t[2] = n;
  n = fminf(t[3], c); c = fmaxf(t[3], c); t[3] = n;
  t[4] = fminf(t[4], c);
}

constexpr int NT3 = N / 128;                   // 24
constexpr int NTILE3 = NT3 * (NT3 + 1) / 2;    // 300

// ---------------- P1: GEMM (3-term bf16 MFMA), NO dist store; emits part5 only ----------------
// part5[b][slot(48)][q(6)][N]  (q0..4 = sorted top-5 asc, q5 = max)
__global__ __launch_bounds__(256) void k_gemm1(const u16* __restrict__ xhi, const u16* __restrict__ xlo,
                                               const float* __restrict__ sq,
                                               float* __restrict__ part5) {
  constexpr int ASTR = 40;
  __shared__ __align__(16) char smem[40960];
  u16* sAh = (u16*)smem;
  u16* sAl = sAh + 128 * ASTR;
  u16* sBh = sAl + 128 * ASTR;
  u16* sBl = sBh + 128 * ASTR;

  int b = blockIdx.y;
  int idx = blockIdx.x;
  int ti = 0, rem = idx;
  while (rem >= NT3 - ti) { rem -= NT3 - ti; ++ti; }
  int tj = ti + rem;
  int i0 = ti * 128, j0 = tj * 128;
  bool do_mirror = (ti != tj);

  const float* sqb = sq + (size_t)b * N;

  int tid = threadIdx.x;
  int srow = tid >> 1, shalf = (tid & 1) * 16;
  const u16* gAh = xhi + ((size_t)b * N + i0 + srow) * C + shalf;
  const u16* gAl = xlo + ((size_t)b * N + i0 + srow) * C + shalf;
  const u16* gBh = xhi + ((size_t)b * N + j0 + srow) * C + shalf;
  const u16* gBl = xlo + ((size_t)b * N + j0 + srow) * C + shalf;
  int wofs = srow * ASTR + shalf;

  int lane = tid & 63, w = tid >> 6;
  int wr = (w >> 1) * 64, wc = (w & 1) * 64;
  int l15 = lane & 15, l4 = lane >> 4;

  f32x4 acc[4][4];
#pragma unroll
  for (int rt = 0; rt < 4; ++rt)
#pragma unroll
    for (int ct = 0; ct < 4; ++ct)
#pragma unroll
      for (int e = 0; e < 4; ++e) acc[rt][ct][e] = 0.f;

  uint4 p0 = *(const uint4*)gAh, p1 = *(const uint4*)(gAh + 8);
  uint4 p2 = *(const uint4*)gAl, p3 = *(const uint4*)(gAl + 8);
  uint4 p4 = *(const uint4*)gBh, p5 = *(const uint4*)(gBh + 8);
  uint4 p6 = *(const uint4*)gBl, p7 = *(const uint4*)(gBl + 8);

  for (int k0 = 0; k0 < C; k0 += 32) {
    *(uint4*)&sAh[wofs] = p0; *(uint4*)&sAh[wofs + 8] = p1;
    *(uint4*)&sAl[wofs] = p2; *(uint4*)&sAl[wofs + 8] = p3;
    *(uint4*)&sBh[wofs] = p4; *(uint4*)&sBh[wofs + 8] = p5;
    *(uint4*)&sBl[wofs] = p6; *(uint4*)&sBl[wofs + 8] = p7;
    __syncthreads();
    int kn = k0 + 32;
    if (kn < C) {
      p0 = *(const uint4*)(gAh + kn); p1 = *(const uint4*)(gAh + kn + 8);
      p2 = *(const uint4*)(gAl + kn); p3 = *(const uint4*)(gAl + kn + 8);
      p4 = *(const uint4*)(gBh + kn); p5 = *(const uint4*)(gBh + kn + 8);
      p6 = *(const uint4*)(gBl + kn); p7 = *(const uint4*)(gBl + kn + 8);
    }
    s16x8 ah[4], al[4];
#pragma unroll
    for (int rt = 0; rt < 4; ++rt) {
      int ro = (wr + rt * 16 + l15) * ASTR + l4 * 8;
      ah[rt] = *(const s16x8*)&sAh[ro];
      al[rt] = *(const s16x8*)&sAl[ro];
    }
#pragma unroll
    for (int ct = 0; ct < 4; ++ct) {
      int co = (wc + ct * 16 + l15) * ASTR + l4 * 8;
      s16x8 bh = *(const s16x8*)&sBh[co];
      s16x8 bl = *(const s16x8*)&sBl[co];
#pragma unroll
      for (int rt = 0; rt < 4; ++rt) {
        acc[rt][ct] = __builtin_amdgcn_mfma_f32_16x16x32_bf16(ah[rt], bh, acc[rt][ct], 0, 0, 0);
        acc[rt][ct] = __builtin_amdgcn_mfma_f32_16x16x32_bf16(ah[rt], bl, acc[rt][ct], 0, 0, 0);
        acc[rt][ct] = __builtin_amdgcn_mfma_f32_16x16x32_bf16(al[rt], bh, acc[rt][ct], 0, 0, 0);
      }
    }
    __syncthreads();   // also guards smem reuse by the epilogue below
  }

  const float SQC = 22.627416997969522f;
  float sqi[4][4], sqj[4];
#pragma unroll
  for (int rt = 0; rt < 4; ++rt)
#pragma unroll
    for (int r = 0; r < 4; ++r) sqi[rt][r] = sqb[i0 + wr + rt * 16 + l4 * 4 + r];
#pragma unroll
  for (int ct = 0; ct < 4; ++ct) sqj[ct] = sqb[j0 + wc + ct * 16 + l15];

#pragma unroll
  for (int rt = 0; rt < 4; ++rt)
#pragma unroll
    for (int ct = 0; ct < 4; ++ct)
#pragma unroll
      for (int r = 0; r < 4; ++r) {
        float d2 = fmaxf(sqi[rt][r] + sqj[ct] - 2.0f * acc[rt][ct][r], 0.0f);
        acc[rt][ct][r] = sqrtf(d2) / SQC;
      }

  // per-wave LDS transpose; top-5 partial scans (no dist store)
  constexpr int TSTR = 76;
  float* sT = (float*)smem + w * (32 * TSTR);

  float t5A[5] = {FLT_MAX, FLT_MAX, FLT_MAX, FLT_MAX, FLT_MAX};
  float mxA = 0.f;

#pragma unroll
  for (int p = 0; p < 2; ++p) {
#pragma unroll
    for (int cth = 0; cth < 2; ++cth) {
      int ct = p * 2 + cth;
      int cl = cth * 16 + l15;
#pragma unroll
      for (int rt = 0; rt < 4; ++rt)
#pragma unroll
        for (int r = 0; r < 4; ++r)
          sT[cl * TSTR + rt * 16 + l4 * 4 + r] = acc[rt][ct][r];
    }
    // A-side: lane owns row rl=lane over this pass's 32 cols
    for (int c = 0; c < 32; ++c) {
      float v = sT[c * TSTR + lane];
      mxA = fmaxf(mxA, v);
      ins5b(t5A, v);
    }
    // mirror side: 2 lanes per col (halves of 64 rows), then merge
    if (do_mirror) {
      int cl = lane & 31, half = lane >> 5;
      float t5B[5] = {FLT_MAX, FLT_MAX, FLT_MAX, FLT_MAX, FLT_MAX};
      float mxB = 0.f;
      for (int k = 0; k < 32; ++k) {
        float v = sT[cl * TSTR + half * 32 + k];
        mxB = fmaxf(mxB, v);
        ins5b(t5B, v);
      }
      mxB = fmaxf(mxB, __shfl_xor(mxB, 32, 64));
      float o0 = __shfl_xor(t5B[0], 32, 64);
      float o1 = __shfl_xor(t5B[1], 32, 64);
      float o2 = __shfl_xor(t5B[2], 32, 64);
      float o3 = __shfl_xor(t5B[3], 32, 64);
      float o4 = __shfl_xor(t5B[4], 32, 64);
      ins5b(t5B, o0); ins5b(t5B, o1); ins5b(t5B, o2); ins5b(t5B, o3); ins5b(t5B, o4);
      if (half == 0) {
        int rowB = j0 + wc + p * 32 + cl;
        int slotB = ti * 2 + (wr >> 6);
        float* dst = part5 + (((size_t)b * 48 + slotB) * 6) * N + rowB;
        dst[0] = t5B[0]; dst[(size_t)N] = t5B[1]; dst[2 * (size_t)N] = t5B[2];
        dst[3 * (size_t)N] = t5B[3]; dst[4 * (size_t)N] = t5B[4]; dst[5 * (size_t)N] = mxB;
      }
    }
  }
  {
    int rowA = i0 + wr + lane;
    int slotA = tj * 2 + (wc >> 6);
    float* dst = part5 + (((size_t)b * 48 + slotA) * 6) * N + rowA;
    dst[0] = t5A[0]; dst[(size_t)N] = t5A[1]; dst[2 * (size_t)N] = t5A[2];
    dst[3 * (size_t)N] = t5A[3]; dst[4 * (size_t)N] = t5A[4]; dst[5 * (size_t)N] = mxA;
  }
}

// ---------------- density from 48-slot partials ----------------
__global__ __launch_bounds__(256) void k_dens(const float* __restrict__ part5,
                                              float* __restrict__ density,
                                              float* __restrict__ rowmax) {
  int g = blockIdx.x * 256 + threadIdx.x;   // b*N + r
  int b = g / N, r = g % N;
  const float* base = part5 + (size_t)b * 48 * 6 * N + r;
  float t5[5] = {FLT_MAX, FLT_MAX, FLT_MAX, FLT_MAX, FLT_MAX};
  float mx = 0.f;
  for (int s = 0; s < 48; ++s) {
    const float* sp = base + (size_t)s * 6 * N;
    ins5b(t5, sp[0]);
    ins5b(t5, sp[(size_t)N]);
    ins5b(t5, sp[2 * (size_t)N]);
    ins5b(t5, sp[3 * (size_t)N]);
    ins5b(t5, sp[4 * (size_t)N]);
    mx = fmaxf(mx, sp[5 * (size_t)N]);
  }
  float sum = t5[0] * t5[0] + t5[1] * t5[1] + t5[2] * t5[2] + t5[3] * t5[3] + t5[4] * t5[4];
  density[g] = expf(-(sum / 5.0f)) + jax_uniform_bn(g) * 1e-6f;
  rowmax[g] = mx;
}

// ---------------- distmax[b] ----------------
__global__ __launch_bounds__(1024) void k_dmax(const float* __restrict__ rowmax,
                                               float* __restrict__ distmax) {
  __shared__ float red[16];
  int b = blockIdx.x;
  int tid = threadIdx.x;
  const float* rb = rowmax + (size_t)b * N;
  float mx = 0.f;
  for (int j = tid; j < N; j += 1024) mx = fmaxf(mx, rb[j]);
#pragma unroll
  for (int m = 1; m < 64; m <<= 1) mx = fmaxf(mx, __shfl_xor(mx, m, 64));
  if ((tid & 63) == 0) red[tid >> 6] = mx;
  __syncthreads();
  if (tid == 0) {
    float r = red[0];
#pragma unroll
    for (int q = 1; q < 16; ++q) r = fmaxf(r, red[q]);
    distmax[b] = r;
  }
}

// ---------------- P2: GEMM recompute; masked-min partials per (row, 64-col slot) ----------------
// partmin[b][slot(48)][N], seeded FLT_MAX (dmax applied in k_score).
__global__ __launch_bounds__(256) void k_gemm2(const u16* __restrict__ xhi, const u16* __restrict__ xlo,
                                               const float* __restrict__ sq,
                                               const float* __restrict__ density,
                                               float* __restrict__ partmin) {
  constexpr int ASTR = 40;
  __shared__ __align__(16) char smem[40960];
  u16* sAh = (u16*)smem;
  u16* sAl = sAh + 128 * ASTR;
  u16* sBh = sAl + 128 * ASTR;
  u16* sBl = sBh + 128 * ASTR;

  int b = blockIdx.y;
  int idx = blockIdx.x;
  int ti = 0, rem = idx;
  while (rem >= NT3 - ti) { rem -= NT3 - ti; ++ti; }
  int tj = ti + rem;
  int i0 = ti * 128, j0 = tj * 128;
  bool do_mirror = (ti != tj);

  const float* sqb = sq + (size_t)b * N;

  int tid = threadIdx.x;
  int srow = tid >> 1, shalf = (tid & 1) * 16;
  const u16* gAh = xhi + ((size_t)b * N + i0 + srow) * C + shalf;
  const u16* gAl = xlo + ((size_t)b * N + i0 + srow) * C + shalf;
  const u16* gBh = xhi + ((size_t)b * N + j0 + srow) * C + shalf;
  const u16* gBl = xlo + ((size_t)b * N + j0 + srow) * C + shalf;
  int wofs = srow * ASTR + shalf;

  int lane = tid & 63, w = tid >> 6;
  int wr = (w >> 1) * 64, wc = (w & 1) * 64;
  int l15 = lane & 15, l4 = lane >> 4;

  f32x4 acc[4][4];
#pragma unroll
  for (int rt = 0; rt < 4; ++rt)
#pragma unroll
    for (int ct = 0; ct < 4; ++ct)
#pragma unroll
      for (int e = 0; e < 4; ++e) acc[rt][ct][e] = 0.f;

  uint4 p0 = *(const uint4*)gAh, p1 = *(const uint4*)(gAh + 8);
  uint4 p2 = *(const uint4*)gAl, p3 = *(const uint4*)(gAl + 8);
  uint4 p4 = *(const uint4*)gBh, p5 = *(const uint4*)(gBh + 8);
  uint4 p6 = *(const uint4*)gBl, p7 = *(const uint4*)(gBl + 8);

  for (int k0 = 0; k0 < C; k0 += 32) {
    *(uint4*)&sAh[wofs] = p0; *(uint4*)&sAh[wofs + 8] = p1;
    *(uint4*)&sAl[wofs] = p2; *(uint4*)&sAl[wofs + 8] = p3;
    *(uint4*)&sBh[wofs] = p4; *(uint4*)&sBh[wofs + 8] = p5;
    *(uint4*)&sBl[wofs] = p6; *(uint4*)&sBl[wofs + 8] = p7;
    __syncthreads();
    int kn = k0 + 32;
    if (kn < C) {
      p0 = *(const uint4*)(gAh + kn); p1 = *(const uint4*)(gAh + kn + 8);
      p2 = *(const uint4*)(gAl + kn); p3 = *(const uint4*)(gAl + kn + 8);
      p4 = *(const uint4*)(gBh + kn); p5 = *(const uint4*)(gBh + kn + 8);
      p6 = *(const uint4*)(gBl + kn); p7 = *(const uint4*)(gBl + kn + 8);
    }
    s16x8 ah[4], al[4];
#pragma unroll
    for (int rt = 0; rt < 4; ++rt) {
      int ro = (wr + rt * 16 + l15) * ASTR + l4 * 8;
      ah[rt] = *(const s16x8*)&sAh[ro];
      al[rt] = *(const s16x8*)&sAl[ro];
    }
#pragma unroll
    for (int ct = 0; ct < 4; ++ct) {
      int co = (wc + ct * 16 + l15) * ASTR + l4 * 8;
      s16x8 bh = *(const s16x8*)&sBh[co];
      s16x8 bl = *(const s16x8*)&sBl[co];
#pragma unroll
      for (int rt = 0; rt < 4; ++rt) {
        acc[rt][ct] = __builtin_amdgcn_mfma_f32_16x16x32_bf16(ah[rt], bh, acc[rt][ct], 0, 0, 0);
        acc[rt][ct] = __builtin_amdgcn_mfma_f32_16x16x32_bf16(ah[rt], bl, acc[rt][ct], 0, 0, 0);
        acc[rt][ct] = __builtin_amdgcn_mfma_f32_16x16x32_bf16(al[rt], bh, acc[rt][ct], 0, 0, 0);
      }
    }
    __syncthreads();
  }

  const float SQC = 22.627416997969522f;
  float sqi[4][4], sqj[4];
#pragma unroll
  for (int rt = 0; rt < 4; ++rt)
#pragma unroll
    for (int r = 0; r < 4; ++r) sqi[rt][r] = sqb[i0 + wr + rt * 16 + l4 * 4 + r];
#pragma unroll
  for (int ct = 0; ct < 4; ++ct) sqj[ct] = sqb[j0 + wc + ct * 16 + l15];

#pragma unroll
  for (int rt = 0; rt < 4; ++rt)
#pragma unroll
    for (int ct = 0; ct < 4; ++ct)
#pragma unroll
      for (int r = 0; r < 4; ++r) {
        float d2 = fmaxf(sqi[rt][r] + sqj[ct] - 2.0f * acc[rt][ct][r], 0.0f);
        acc[rt][ct][r] = sqrtf(d2) / SQC;
      }

  // epilogue: per-wave transpose + masked-min partials
  constexpr int TSTR = 76;
  float* sT  = (float*)smem + w * (32 * TSTR);
  float* sDc = (float*)smem + 4 * (32 * TSTR) + w * 128;  // [0..63] col dens
  float* sDr = sDc + 64;                                  // [64..127] row dens
  const float* db = density + (size_t)b * N;
  float dureg = db[i0 + wr + lane];      // density of this lane's A-row
  float dcreg = db[j0 + wc + lane];      // density of this lane's col
  sDr[lane] = dureg;
  sDc[lane] = dcreg;

  float mnA = FLT_MAX;
#pragma unroll
  for (int p = 0; p < 2; ++p) {
#pragma unroll
    for (int cth = 0; cth < 2; ++cth) {
      int ct = p * 2 + cth;
      int cl = cth * 16 + l15;
#pragma unroll
      for (int rt = 0; rt < 4; ++rt)
#pragma unroll
        for (int r = 0; r < 4; ++r)
          sT[cl * TSTR + rt * 16 + l4 * 4 + r] = acc[rt][ct][r];
    }
    // A-side masked min: row u = i0+wr+lane over this pass's 32 cols
    for (int c = 0; c < 32; ++c) {
      float v = sT[c * TSTR + lane];
      float dc = sDc[p * 32 + c];
      mnA = fminf(mnA, (dc > dureg) ? v : FLT_MAX);
    }
    // mirror side: rows v = cols of this tile; masked by dens of A-rows
    if (do_mirror) {
      int cl = lane & 31, half = lane >> 5;
      float dv = sDc[p * 32 + cl];
      float mnB = FLT_MAX;
      for (int k = 0; k < 32; ++k) {
        float du = sDr[half * 32 + k];
        float v = sT[cl * TSTR + half * 32 + k];
        mnB = fminf(mnB, (du > dv) ? v : FLT_MAX);
      }
      mnB = fminf(mnB, __shfl_xor(mnB, 32, 64));
      if (half == 0) {
        int rowB = j0 + wc + p * 32 + cl;
        int slotB = ti * 2 + (wr >> 6);
        partmin[((size_t)b * 48 + slotB) * N + rowB] = mnB;
      }
    }
  }
  {
    int rowA = i0 + wr + lane;
    int slotA = tj * 2 + (wc >> 6);
    partmin[((size_t)b * 48 + slotA) * N + rowA] = mnA;
  }
}

// ---------------- score = density * min(dmax, min over 48 slot-partials) ----------------
__global__ void k_score(const float* __restrict__ partmin, const float* __restrict__ density,
                        const float* __restrict__ distmax, float* __restrict__ score) {
  int g = blockIdx.x * 256 + threadIdx.x;   // b*N + r
  int b = g / N, r = g % N;
  float mn = distmax[b];
  const float* base = partmin + (size_t)b * 48 * N + r;
#pragma unroll
  for (int s = 0; s < 48; ++s) mn = fminf(mn, base[(size_t)s * N]);
  score[g] = mn * density[g];
}

// ---------------- counting-rank top-CL ----------------
__global__ __launch_bounds__(256) void k_rank(const float* __restrict__ score,
                                              int* __restrict__ index_down,
                                              int* __restrict__ rank) {
  __shared__ float ssc[N];
  int tid = threadIdx.x;
  int wv = tid >> 6, lane = tid & 63;
  int i = blockIdx.x * 4 + wv;
  int b = blockIdx.y;
  const float* sb = score + (size_t)b * N;
  for (int j = tid * 4; j < N; j += 1024) *(float4*)(ssc + j) = *(const float4*)(sb + j);
  __syncthreads();
  float si = ssc[i];
  int cnt = 0;
#pragma unroll
  for (int it = 0; it < N / 256; ++it) {
    int j = it * 256 + lane * 4;
    float4 v = *(const float4*)(ssc + j);
    cnt += (v.x > si) || (v.x == si && (j + 0) < i);
    cnt += (v.y > si) || (v.y == si && (j + 1) < i);
    cnt += (v.z > si) || (v.z == si && (j + 2) < i);
    cnt += (v.w > si) || (v.w == si && (j + 3) < i);
  }
#pragma unroll
  for (int m = 1; m < 64; m <<= 1) cnt += __shfl_xor(cnt, m, 64);
  if (lane == 0) {
    rank[b * N + i] = (cnt < CL) ? cnt : -1;
    if (cnt < CL) index_down[b * CL + cnt] = i;
  }
}

// ---------------- P3: center-GEMM (gathered A = centers) + packed argmin ----------------
__global__ __launch_bounds__(256) void k_assign2(const u16* __restrict__ xhi, const u16* __restrict__ xlo,
                                                 const float* __restrict__ sq,
                                                 const int* __restrict__ index_down,
                                                 unsigned long long* __restrict__ packed) {
  constexpr int ASTR = 40;
  __shared__ __align__(16) char smem[40960];
  u16* sAh = (u16*)smem;
  u16* sAl = sAh + 128 * ASTR;
  u16* sBh = sAl + 128 * ASTR;
  u16* sBl = sBh + 128 * ASTR;

  int jt = blockIdx.x;        // token tile (24)
  int rt_blk = blockIdx.y;    // center tile (6)
  int b = blockIdx.z;
  int j0 = jt * 128, r0 = rt_blk * 128;

  const float* sqb = sq + (size_t)b * N;
  const int* idb = index_down + (size_t)b * CL;

  int tid = threadIdx.x;
  int srow = tid >> 1, shalf = (tid & 1) * 16;
  int cid = idb[r0 + srow];   // gathered center token index
  const u16* gAh = xhi + ((size_t)b * N + cid) * C + shalf;
  const u16* gAl = xlo + ((size_t)b * N + cid) * C + shalf;
  const u16* gBh = xhi + ((size_t)b * N + j0 + srow) * C + shalf;
  const u16* gBl = xlo + ((size_t)b * N + j0 + srow) * C + shalf;
  int wofs = srow * ASTR + shalf;

  int lane = tid & 63, w = tid >> 6;
  int wr = (w >> 1) * 64, wc = (w & 1) * 64;
  int l15 = lane & 15, l4 = lane >> 4;

  f32x4 acc[4][4];
#pragma unroll
  for (int rt = 0; rt < 4; ++rt)
#pragma unroll
    for (int ct = 0; ct < 4; ++ct)
#pragma unroll
      for (int e = 0; e < 4; ++e) acc[rt][ct][e] = 0.f;

  uint4 p0 = *(const uint4*)gAh, p1 = *(const uint4*)(gAh + 8);
  uint4 p2 = *(const uint4*)gAl, p3 = *(const uint4*)(gAl + 8);
  uint4 p4 = *(const uint4*)gBh, p5 = *(const uint4*)(gBh + 8);
  uint4 p6 = *(const uint4*)gBl, p7 = *(const uint4*)(gBl + 8);

  for (int k0 = 0; k0 < C; k0 += 32) {
    *(uint4*)&sAh[wofs] = p0; *(uint4*)&sAh[wofs + 8] = p1;
    *(uint4*)&sAl[wofs] = p2; *(uint4*)&sAl[wofs + 8] = p3;
    *(uint4*)&sBh[wofs] = p4; *(uint4*)&sBh[wofs + 8] = p5;
    *(uint4*)&sBl[wofs] = p6; *(uint4*)&sBl[wofs + 8] = p7;
    __syncthreads();
    int kn = k0 + 32;
    if (kn < C) {
      p0 = *(const uint4*)(gAh + kn); p1 = *(const uint4*)(gAh + kn + 8);
      p2 = *(const uint4*)(gAl + kn); p3 = *(const uint4*)(gAl + kn + 8);
      p4 = *(const uint4*)(gBh + kn); p5 = *(const uint4*)(gBh + kn + 8);
      p6 = *(const uint4*)(gBl + kn); p7 = *(const uint4*)(gBl + kn + 8);
    }
    s16x8 ah[4], al[4];
#pragma unroll
    for (int rt = 0; rt < 4; ++rt) {
      int ro = (wr + rt * 16 + l15) * ASTR + l4 * 8;
      ah[rt] = *(const s16x8*)&sAh[ro];
      al[rt] = *(const s16x8*)&sAl[ro];
    }
#pragma unroll
    for (int ct = 0; ct < 4; ++ct) {
      int co = (wc + ct * 16 + l15) * ASTR + l4 * 8;
      s16x8 bh = *(const s16x8*)&sBh[co];
      s16x8 bl = *(const s16x8*)&sBl[co];
#pragma unroll
      for (int rt = 0; rt < 4; ++rt) {
        acc[rt][ct] = __builtin_amdgcn_mfma_f32_16x16x32_bf16(ah[rt], bh, acc[rt][ct], 0, 0, 0);
        acc[rt][ct] = __builtin_amdgcn_mfma_f32_16x16x32_bf16(ah[rt], bl, acc[rt][ct], 0, 0, 0);
        acc[rt][ct] = __builtin_amdgcn_mfma_f32_16x16x32_bf16(al[rt], bh, acc[rt][ct], 0, 0, 0);
      }
    }
    __syncthreads();
  }

  const float SQC = 22.627416997969522f;
  float sqi[4][4];
  int cidx[4][4];
#pragma unroll
  for (int rt = 0; rt < 4; ++rt)
#pragma unroll
    for (int r = 0; r < 4; ++r) {
      int rr = r0 + wr + rt * 16 + l4 * 4 + r;     // rank position (argmin value)
      cidx[rt][r] = rr;
      sqi[rt][r] = sqb[idb[rr]];
    }
  float sqj[4];
#pragma unroll
  for (int ct = 0; ct < 4; ++ct) sqj[ct] = sqb[j0 + wc + ct * 16 + l15];

#pragma unroll
  for (int ct = 0; ct < 4; ++ct) {
    unsigned long long best = ~0ull;
#pragma unroll
    for (int rt = 0; rt < 4; ++rt)
#pragma unroll
      for (int r = 0; r < 4; ++r) {
        float d2 = fmaxf(sqi[rt][r] + sqj[ct] - 2.0f * acc[rt][ct][r], 0.0f);
        float d = sqrtf(d2) / SQC;
        unsigned long long key = ((unsigned long long)__float_as_uint(d) << 32) | (unsigned)cidx[rt][r];
        best = (key < best) ? key : best;
      }
    unsigned long long o;
    o = __shfl_xor(best, 16, 64); best = (o < best) ? o : best;
    o = __shfl_xor(best, 32, 64); best = (o < best) ? o : best;
    if (l4 == 0) atomicMin(&packed[(size_t)b * N + j0 + wc + ct * 16 + l15], best);
  }
}

// ---------------- final assignment + histogram ----------------
__global__ void k_assign_fin2(const unsigned long long* __restrict__ packed,
                              const int* __restrict__ rank,
                              int* __restrict__ idx_cluster, int* __restrict__ counts) {
  int g = blockIdx.x * 256 + threadIdx.x;
  int b = g / N;
  int r = rank[g];
  int cl = (r >= 0) ? r : (int)(unsigned)(packed[g] & 0xffffffffull);
  idx_cluster[g] = cl;
  atomicAdd(&counts[b * CL + cl], 1);
}

// ---------------- merge ----------------
__global__ __launch_bounds__(1024) void k_scan(const int* __restrict__ counts,
                                               int* __restrict__ offsets, int* __restrict__ cursor) {
  constexpr int T = B * CL;
  __shared__ int sm[T];
  int tid = threadIdx.x;
  for (int p = tid; p < T; p += 1024) sm[p] = counts[p];
  __syncthreads();
  for (int off = 1; off < T; off <<= 1) {
    int v[3]; int n = 0;
    for (int p = tid; p < T; p += 1024) { v[n++] = (p >= off) ? sm[p - off] : 0; }
    __syncthreads();
    n = 0;
    for (int p = tid; p < T; p += 1024) { sm[p] += v[n++]; }
    __syncthreads();
  }
  for (int p = tid; p < T; p += 1024) {
    int e = sm[p] - counts[p];
    offsets[p] = e; cursor[p] = e;
  }
}

__global__ void k_fill(const int* __restrict__ idx_cluster, int* __restrict__ cursor,
                       int* __restrict__ members) {
  int g = blockIdx.x * 256 + threadIdx.x;
  int b = g / N, i = g % N;
  int seg = b * CL + idx_cluster[g];
  int pos = atomicAdd(&cursor[seg], 1);
  members[pos] = i;
}

__global__ __launch_bounds__(128) void k_gather(const float* __restrict__ x, const int* __restrict__ members,
                                                const int* __restrict__ offsets, const int* __restrict__ counts,
                                                float* __restrict__ out0) {
  int seg = blockIdx.x;
  int b = seg / CL;
  int cnt = counts[seg], off = offsets[seg];
  float nw = 1.0f / ((float)cnt + 1e-6f);
  int c = threadIdx.x * 4;
  const float* xb = x + (size_t)b * N * C;
  float4 acc = make_float4(0.f, 0.f, 0.f, 0.f);
  for (int m = 0; m < cnt; ++m) {
    int tok = members[off + m];
    float4 v = *(const float4*)(xb + (size_t)tok * C + c);
    acc.x += v.x * nw; acc.y += v.y * nw; acc.z += v.z * nw; acc.w += v.w * nw;
  }
  *(float4*)(out0 + (size_t)seg * C + c) = acc;
}

__global__ void k_final(const float* __restrict__ agg_weight, const int* __restrict__ idx_token,
                        const int* __restrict__ idx_cluster, const int* __restrict__ counts,
                        float* __restrict__ out1, float* __restrict__ out2, float* __restrict__ out3) {
  int g = blockIdx.x * 256 + threadIdx.x;
  int b = g / N;
  int it = idx_token[g];
  int clt = idx_cluster[b * N + it];
  float nwt = 1.0f / ((float)counts[b * CL + clt] + 1e-6f);
  out1[g] = agg_weight[g] * nwt;
  out2[g] = (float)clt;
  out3[g] = (float)idx_cluster[g];
}

// ---------------- launch ----------------
extern "C" void kernel_launch(void* const* d_in, const int* in_sizes, int n_in,
                              void* d_out, int out_size, void* d_ws, size_t ws_size,
                              hipStream_t stream) {
  const float* x          = (const float*)d_in[0];
  const int*   idx_token  = (const int*)d_in[1];
  const float* agg_weight = (const float*)d_in[2];

  float* out0 = (float*)d_out;
  float* out1 = out0 + (size_t)B * CL * C;
  float* out2 = out1 + (size_t)B * N;
  float* out3 = out2 + (size_t)B * N;

  char* w = (char*)d_ws;
  auto carve = [&](size_t bytes) { char* p = w; w += (bytes + 255) & ~(size_t)255; return p; };
  float*    sq         = (float*)carve((size_t)B * N * 4);
  float*    density    = (float*)carve((size_t)B * N * 4);
  float*    score      = (float*)carve((size_t)B * N * 4);
  float*    rowmax     = (float*)carve((size_t)B * N * 4);
  float*    distmax    = (float*)carve((size_t)B * 4);
  int*      index_down = (int*)carve((size_t)B * CL * 4);
  int*      rank       = (int*)carve((size_t)B * N * 4);
  int*      idx_clus   = (int*)carve((size_t)B * N * 4);
  int*      counts     = (int*)carve((size_t)B * CL * 4);
  int*      offsets    = (int*)carve((size_t)B * CL * 4);
  int*      cursor     = (int*)carve((size_t)B * CL * 4);
  int*      members    = (int*)carve((size_t)B * N * 4);
  unsigned long long* packed = (unsigned long long*)carve((size_t)B * N * 8);
  u16*      xhi        = (u16*)carve((size_t)B * N * C * 2);
  u16*      xlo        = (u16*)carve((size_t)B * N * C * 2);
  float*    part5      = (float*)carve((size_t)B * 48 * 6 * N * 4);
  float*    partmin    = (float*)carve((size_t)B * 48 * N * 4);
  (void)ws_size;

  k_prep<<<B * N, 64, 0, stream>>>(x, sq, xhi, xlo, counts, packed);
  k_gemm1<<<dim3(NTILE3, B), 256, 0, stream>>>(xhi, xlo, sq, part5);
  k_dens<<<(B * N) / 256, 256, 0, stream>>>(part5, density, rowmax);
  k_dmax<<<B, 1024, 0, stream>>>(rowmax, distmax);
  k_gemm2<<<dim3(NTILE3, B), 256, 0, stream>>>(xhi, xlo, sq, density, partmin);
  k_score<<<(B * N) / 256, 256, 0, stream>>>(partmin, density, distmax, score);
  k_rank<<<dim3(N / 4, B), 256, 0, stream>>>(score, index_down, rank);
  k_assign2<<<dim3(NT3, CL / 128, B), 256, 0, stream>>>(xhi, xlo, sq, index_down, packed);
  k_assign_fin2<<<(B * N) / 256, 256, 0, stream>>>(packed, rank, idx_clus, counts);
  k_scan<<<1, 1024, 0, stream>>>(counts, offsets, cursor);
  k_fill<<<(B * N) / 256, 256, 0, stream>>>(idx_clus, cursor, members);
  k_gather<<<B * CL, 128, 0, stream>>>(x, members, offsets, counts, out0);
  k_final<<<(B * N) / 256, 256, 0, stream>>>(agg_weight, idx_token, idx_clus, counts, out1, out2, out3);
}

// Round 13
// 301.746 us; speedup vs baseline: 1.3074x; 1.3074x over previous
//
#include <hip/hip_runtime.h>
#include <math.h>
#include <float.h>

constexpr int B  = 4;
constexpr int N  = 3072;
constexpr int C  = 512;
constexpr int CL = 768;

typedef unsigned short u16;
typedef __attribute__((ext_vector_type(8))) short s16x8;
typedef __attribute__((ext_vector_type(4))) float f32x4;

// ---------------- JAX threefry2x32 (exact) ----------------
__device__ __forceinline__ unsigned rotl32(unsigned v, int d) { return (v << d) | (v >> (32 - d)); }

__device__ inline void threefry2x32(unsigned k0, unsigned k1, unsigned c0, unsigned c1,
                                    unsigned& o0, unsigned& o1) {
  unsigned ks0 = k0, ks1 = k1, ks2 = 0x1BD11BDAu ^ k0 ^ k1;
  unsigned x0 = c0 + ks0, x1 = c1 + ks1;
#define TF_RND(r) { x0 += x1; x1 = rotl32(x1, (r)); x1 ^= x0; }
  TF_RND(13) TF_RND(15) TF_RND(26) TF_RND(6)  x0 += ks1; x1 += ks2 + 1u;
  TF_RND(17) TF_RND(29) TF_RND(16) TF_RND(24) x0 += ks2; x1 += ks0 + 2u;
  TF_RND(13) TF_RND(15) TF_RND(26) TF_RND(6)  x0 += ks0; x1 += ks1 + 3u;
  TF_RND(17) TF_RND(29) TF_RND(16) TF_RND(24) x0 += ks1; x1 += ks2 + 4u;
  TF_RND(13) TF_RND(15) TF_RND(26) TF_RND(6)  x0 += ks2; x1 += ks0 + 5u;
#undef TF_RND
  o0 = x0; o1 = x1;
}

__device__ inline float jax_uniform_bn(int f) {
  constexpr int HALF = (B * N) / 2;
  unsigned o0, o1, bits;
  if (f < HALF) { threefry2x32(0u, 42u, (unsigned)f, (unsigned)(f + HALF), o0, o1); bits = o0; }
  else          { threefry2x32(0u, 42u, (unsigned)(f - HALF), (unsigned)f, o0, o1); bits = o1; }
  return __uint_as_float((bits >> 9) | 0x3f800000u) - 1.0f;
}

// ---------------- bf16 split helpers ----------------
__device__ __forceinline__ u16 bf16rn(float f) {
  unsigned u = __float_as_uint(f);
  unsigned r = u + 0x7FFFu + ((u >> 16) & 1u);
  return (u16)(r >> 16);
}
__device__ __forceinline__ float bf16tof(u16 h) {
  return __uint_as_float(((unsigned)h) << 16);
}

// ---------------- prep: sq + hi/lo split + init (one wave per row) ----------------
__global__ __launch_bounds__(64) void k_prep(const float* __restrict__ x, float* __restrict__ sq,
                                             u16* __restrict__ xhi, u16* __restrict__ xlo,
                                             int* __restrict__ counts,
                                             unsigned long long* __restrict__ packed) {
  int row = blockIdx.x;   // 0..B*N-1
  int lane = threadIdx.x;
  const float* xr = x + (size_t)row * C;
  u16* hr = xhi + (size_t)row * C;
  u16* lr = xlo + (size_t)row * C;
  float s = 0.f;
  for (int c = lane * 4; c < C; c += 256) {
    float4 v = *(const float4*)(xr + c);
    s += v.x * v.x + v.y * v.y + v.z * v.z + v.w * v.w;
    u16 h0 = bf16rn(v.x), h1 = bf16rn(v.y), h2 = bf16rn(v.z), h3 = bf16rn(v.w);
    u16 l0 = bf16rn(v.x - bf16tof(h0));
    u16 l1 = bf16rn(v.y - bf16tof(h1));
    u16 l2 = bf16rn(v.z - bf16tof(h2));
    u16 l3 = bf16rn(v.w - bf16tof(h3));
    uint2 hp, lp;
    hp.x = (unsigned)h0 | ((unsigned)h1 << 16); hp.y = (unsigned)h2 | ((unsigned)h3 << 16);
    lp.x = (unsigned)l0 | ((unsigned)l1 << 16); lp.y = (unsigned)l2 | ((unsigned)l3 << 16);
    *(uint2*)(hr + c) = hp;
    *(uint2*)(lr + c) = lp;
  }
  for (int o = 32; o > 0; o >>= 1) s += __shfl_down(s, o, 64);
  if (lane == 0) {
    sq[row] = s;
    packed[row] = ~0ull;
    if (row < B * CL) counts[row] = 0;
  }
}

// ---------------- branchless sorted-insert of v into ascending t[0..4] ----------------
__device__ __forceinline__ void ins5b(float t[5], float v) {
  float c = v;
  float n;
  n = fminf(t[0], c); c = fmaxf(t[0], c); t[0] = n;
  n = fminf(t[1], c); c = fmaxf(t[1], c); t[1] = n;
  n = fminf(t[2], c); c = fmaxf(t[2], c); t[2] = n;
  n = fminf(t[3], c); c = fmaxf(t[3], c); t[3] = n;
  t[4] = fminf(t[4], c);
}

constexpr int NT3 = N / 128;                   // 24
constexpr int NTILE3 = NT3 * (NT3 + 1) / 2;    // 300

// ---------------- dist GEMM (3-term bf16 MFMA), 128x128 tile ----------------
// Stores dist (direct + mirror, coalesced via LDS transpose) and per-(row,
// 64-col-slot) 5-NN partials part5[bl][slot(48)][q(6)][N].
// __launch_bounds__(256,3): force combined VGPR+AGPR <= ~170 so 3 waves/SIMD
// fit (was 172 -> 2 waves/SIMD, pipes serialized; see round-12 post-mortem).
__global__ __launch_bounds__(256, 3) void k_distm(const u16* __restrict__ xhi, const u16* __restrict__ xlo,
                                                  const float* __restrict__ sq,
                                                  float* __restrict__ distbuf,
                                                  float* __restrict__ part5, int b0) {
  constexpr int ASTR = 40;
  __shared__ __align__(16) char smem[40960];
  u16* sAh = (u16*)smem;
  u16* sAl = sAh + 128 * ASTR;
  u16* sBh = sAl + 128 * ASTR;
  u16* sBl = sBh + 128 * ASTR;

  int bl = blockIdx.y, b = b0 + bl;
  int idx = blockIdx.x;
  int ti = 0, rem = idx;
  while (rem >= NT3 - ti) { rem -= NT3 - ti; ++ti; }
  int tj = ti + rem;
  int i0 = ti * 128, j0 = tj * 128;
  bool do_mirror = (ti != tj);

  const float* sqb = sq + (size_t)b * N;
  float* dist = distbuf + (size_t)bl * N * N;

  int tid = threadIdx.x;
  int srow = tid >> 1, shalf = (tid & 1) * 16;
  const u16* gAh = xhi + ((size_t)b * N + i0 + srow) * C + shalf;
  const u16* gAl = xlo + ((size_t)b * N + i0 + srow) * C + shalf;
  const u16* gBh = xhi + ((size_t)b * N + j0 + srow) * C + shalf;
  const u16* gBl = xlo + ((size_t)b * N + j0 + srow) * C + shalf;
  int wofs = srow * ASTR + shalf;

  int lane = tid & 63, w = tid >> 6;
  int wr = (w >> 1) * 64, wc = (w & 1) * 64;
  int l15 = lane & 15, l4 = lane >> 4;

  f32x4 acc[4][4];
#pragma unroll
  for (int rt = 0; rt < 4; ++rt)
#pragma unroll
    for (int ct = 0; ct < 4; ++ct)
#pragma unroll
      for (int e = 0; e < 4; ++e) acc[rt][ct][e] = 0.f;

  uint4 p0 = *(const uint4*)gAh, p1 = *(const uint4*)(gAh + 8);
  uint4 p2 = *(const uint4*)gAl, p3 = *(const uint4*)(gAl + 8);
  uint4 p4 = *(const uint4*)gBh, p5 = *(const uint4*)(gBh + 8);
  uint4 p6 = *(const uint4*)gBl, p7 = *(const uint4*)(gBl + 8);

  for (int k0 = 0; k0 < C; k0 += 32) {
    *(uint4*)&sAh[wofs] = p0; *(uint4*)&sAh[wofs + 8] = p1;
    *(uint4*)&sAl[wofs] = p2; *(uint4*)&sAl[wofs + 8] = p3;
    *(uint4*)&sBh[wofs] = p4; *(uint4*)&sBh[wofs + 8] = p5;
    *(uint4*)&sBl[wofs] = p6; *(uint4*)&sBl[wofs + 8] = p7;
    __syncthreads();
    int kn = k0 + 32;
    if (kn < C) {
      p0 = *(const uint4*)(gAh + kn); p1 = *(const uint4*)(gAh + kn + 8);
      p2 = *(const uint4*)(gAl + kn); p3 = *(const uint4*)(gAl + kn + 8);
      p4 = *(const uint4*)(gBh + kn); p5 = *(const uint4*)(gBh + kn + 8);
      p6 = *(const uint4*)(gBl + kn); p7 = *(const uint4*)(gBl + kn + 8);
    }
    s16x8 ah[4], al[4];
#pragma unroll
    for (int rt = 0; rt < 4; ++rt) {
      int ro = (wr + rt * 16 + l15) * ASTR + l4 * 8;
      ah[rt] = *(const s16x8*)&sAh[ro];
      al[rt] = *(const s16x8*)&sAl[ro];
    }
#pragma unroll
    for (int ct = 0; ct < 4; ++ct) {
      int co = (wc + ct * 16 + l15) * ASTR + l4 * 8;
      s16x8 bh = *(const s16x8*)&sBh[co];
      s16x8 bl = *(const s16x8*)&sBl[co];
#pragma unroll
      for (int rt = 0; rt < 4; ++rt) {
        acc[rt][ct] = __builtin_amdgcn_mfma_f32_16x16x32_bf16(ah[rt], bh, acc[rt][ct], 0, 0, 0);
        acc[rt][ct] = __builtin_amdgcn_mfma_f32_16x16x32_bf16(ah[rt], bl, acc[rt][ct], 0, 0, 0);
        acc[rt][ct] = __builtin_amdgcn_mfma_f32_16x16x32_bf16(al[rt], bh, acc[rt][ct], 0, 0, 0);
      }
    }
    __syncthreads();   // also guards smem reuse by the epilogue below
  }

  const float SQC = 22.627416997969522f;
  float sqi[4][4], sqj[4];
#pragma unroll
  for (int rt = 0; rt < 4; ++rt)
#pragma unroll
    for (int r = 0; r < 4; ++r) sqi[rt][r] = sqb[i0 + wr + rt * 16 + l4 * 4 + r];
#pragma unroll
  for (int ct = 0; ct < 4; ++ct) sqj[ct] = sqb[j0 + wc + ct * 16 + l15];

#pragma unroll
  for (int rt = 0; rt < 4; ++rt)
#pragma unroll
    for (int ct = 0; ct < 4; ++ct)
#pragma unroll
      for (int r = 0; r < 4; ++r) {
        float d2 = fmaxf(sqi[rt][r] + sqj[ct] - 2.0f * acc[rt][ct][r], 0.0f);
        acc[rt][ct][r] = sqrtf(d2) / SQC;
      }

  // ---- epilogue: per-wave LDS transpose (32-col passes):
  //  (a) coalesced float4 direct + mirror dist writes
  //  (b) per-row 5-NN partials
  constexpr int TSTR = 76;
  float* sT = (float*)smem + w * (32 * TSTR);

  float t5A[5] = {FLT_MAX, FLT_MAX, FLT_MAX, FLT_MAX, FLT_MAX};
  float mxA = 0.f;

#pragma unroll
  for (int p = 0; p < 2; ++p) {
#pragma unroll
    for (int cth = 0; cth < 2; ++cth) {
      int ct = p * 2 + cth;
      int cl = cth * 16 + l15;
#pragma unroll
      for (int rt = 0; rt < 4; ++rt)
#pragma unroll
        for (int r = 0; r < 4; ++r)
          sT[cl * TSTR + rt * 16 + l4 * 4 + r] = acc[rt][ct][r];
    }
    // direct write
    {
      int g4 = lane & 7, rbase = lane >> 3;
#pragma unroll
      for (int it = 0; it < 8; ++it) {
        int rl = it * 8 + rbase;
        float4 v = make_float4(sT[(4 * g4 + 0) * TSTR + rl],
                               sT[(4 * g4 + 1) * TSTR + rl],
                               sT[(4 * g4 + 2) * TSTR + rl],
                               sT[(4 * g4 + 3) * TSTR + rl]);
        *(float4*)(dist + (size_t)(i0 + wr + rl) * N + j0 + wc + p * 32 + 4 * g4) = v;
      }
    }
    // mirror write
    if (do_mirror) {
      int cg = lane >> 4, rq = lane & 15;
#pragma unroll
      for (int cc = 0; cc < 8; ++cc) {
        int c = cc * 4 + cg;
        float4 v = *(const float4*)&sT[c * TSTR + rq * 4];
        *(float4*)(dist + (size_t)(j0 + wc + p * 32 + c) * N + i0 + wr + rq * 4) = v;
      }
    }
    // (b1) A-side partial scan
    for (int c = 0; c < 32; ++c) {
      float v = sT[c * TSTR + lane];
      mxA = fmaxf(mxA, v);
      ins5b(t5A, v);
    }
    // (b2) mirror-side partials
    if (do_mirror) {
      int cl = lane & 31, half = lane >> 5;
      float t5B[5] = {FLT_MAX, FLT_MAX, FLT_MAX, FLT_MAX, FLT_MAX};
      float mxB = 0.f;
      for (int k = 0; k < 32; ++k) {
        float v = sT[cl * TSTR + half * 32 + k];
        mxB = fmaxf(mxB, v);
        ins5b(t5B, v);
      }
      mxB = fmaxf(mxB, __shfl_xor(mxB, 32, 64));
      float o0 = __shfl_xor(t5B[0], 32, 64);
      float o1 = __shfl_xor(t5B[1], 32, 64);
      float o2 = __shfl_xor(t5B[2], 32, 64);
      float o3 = __shfl_xor(t5B[3], 32, 64);
      float o4 = __shfl_xor(t5B[4], 32, 64);
      ins5b(t5B, o0); ins5b(t5B, o1); ins5b(t5B, o2); ins5b(t5B, o3); ins5b(t5B, o4);
      if (half == 0) {
        int rowB = j0 + wc + p * 32 + cl;
        int slotB = ti * 2 + (wr >> 6);
        float* dst = part5 + (((size_t)bl * 48 + slotB) * 6) * N + rowB;
        dst[0] = t5B[0]; dst[(size_t)N] = t5B[1]; dst[2 * (size_t)N] = t5B[2];
        dst[3 * (size_t)N] = t5B[3]; dst[4 * (size_t)N] = t5B[4]; dst[5 * (size_t)N] = mxB;
      }
    }
  }
  {
    int rowA = i0 + wr + lane;
    int slotA = tj * 2 + (wc >> 6);
    float* dst = part5 + (((size_t)bl * 48 + slotA) * 6) * N + rowA;
    dst[0] = t5A[0]; dst[(size_t)N] = t5A[1]; dst[2 * (size_t)N] = t5A[2];
    dst[3 * (size_t)N] = t5A[3]; dst[4 * (size_t)N] = t5A[4]; dst[5 * (size_t)N] = mxA;
  }
}

// ---------------- density from 48-slot partials ----------------
__global__ __launch_bounds__(256) void k_dens(const float* __restrict__ part5,
                                              float* __restrict__ density,
                                              float* __restrict__ rowmax, int b0) {
  int g = blockIdx.x * 256 + threadIdx.x;   // bl*N + r
  int bl = g / N, r = g % N;
  int b = b0 + bl;
  const float* base = part5 + (size_t)bl * 48 * 6 * N + r;
  float t5[5] = {FLT_MAX, FLT_MAX, FLT_MAX, FLT_MAX, FLT_MAX};
  float mx = 0.f;
  for (int s = 0; s < 48; ++s) {
    const float* sp = base + (size_t)s * 6 * N;
    ins5b(t5, sp[0]);
    ins5b(t5, sp[(size_t)N]);
    ins5b(t5, sp[2 * (size_t)N]);
    ins5b(t5, sp[3 * (size_t)N]);
    ins5b(t5, sp[4 * (size_t)N]);
    mx = fmaxf(mx, sp[5 * (size_t)N]);
  }
  float sum = t5[0] * t5[0] + t5[1] * t5[1] + t5[2] * t5[2] + t5[3] * t5[3] + t5[4] * t5[4];
  density[b * N + r] = expf(-(sum / 5.0f)) + jax_uniform_bn(b * N + r) * 1e-6f;
  rowmax[b * N + r] = mx;
}

// ---------------- distmax[b] ----------------
__global__ __launch_bounds__(1024) void k_dmax(const float* __restrict__ rowmax,
                                               float* __restrict__ distmax) {
  __shared__ float red[16];
  int b = blockIdx.x;
  int tid = threadIdx.x;
  const float* rb = rowmax + (size_t)b * N;
  float mx = 0.f;
  for (int j = tid; j < N; j += 1024) mx = fmaxf(mx, rb[j]);
#pragma unroll
  for (int m = 1; m < 64; m <<= 1) mx = fmaxf(mx, __shfl_xor(mx, m, 64));
  if ((tid & 63) == 0) red[tid >> 6] = mx;
  __syncthreads();
  if (tid == 0) {
    float r = red[0];
#pragma unroll
    for (int q = 1; q < 16; ++q) r = fmaxf(r, red[q]);
    distmax[b] = r;
  }
}

// ---------------- masked min -> score ----------------
__global__ __launch_bounds__(256) void k_maskmin(const float* __restrict__ distbuf,
                                                 const float* __restrict__ density,
                                                 const float* __restrict__ distmax,
                                                 float* __restrict__ score, int b0) {
  __shared__ float sd[N];
  int tid = threadIdx.x;
  int wv = tid >> 6, lane = tid & 63;
  int i = blockIdx.x * 4 + wv;
  int bl = blockIdx.y, b = b0 + bl;
  const float* db = density + (size_t)b * N;
  for (int j = tid * 4; j < N; j += 1024) *(float4*)(sd + j) = *(const float4*)(db + j);
  __syncthreads();
  float di = sd[i];
  float dmax = distmax[b];
  const float* row = distbuf + ((size_t)bl * N + i) * N;
  float mn = dmax;
#pragma unroll
  for (int it = 0; it < N / 256; ++it) {
    int j = it * 256 + lane * 4;
    float4 v = *(const float4*)(row + j);
    float4 d = *(const float4*)(sd + j);
    mn = fminf(mn, (d.x > di) ? v.x : dmax);
    mn = fminf(mn, (d.y > di) ? v.y : dmax);
    mn = fminf(mn, (d.z > di) ? v.z : dmax);
    mn = fminf(mn, (d.w > di) ? v.w : dmax);
  }
#pragma unroll
  for (int m = 1; m < 64; m <<= 1) mn = fminf(mn, __shfl_xor(mn, m, 64));
  if (lane == 0) score[b * N + i] = mn * di;
}

// ---------------- counting-rank top-CL ----------------
__global__ __launch_bounds__(256) void k_rank(const float* __restrict__ score,
                                              int* __restrict__ index_down,
                                              int* __restrict__ rank, int b0) {
  __shared__ float ssc[N];
  int tid = threadIdx.x;
  int wv = tid >> 6, lane = tid & 63;
  int i = blockIdx.x * 4 + wv;
  int b = b0 + blockIdx.y;
  const float* sb = score + (size_t)b * N;
  for (int j = tid * 4; j < N; j += 1024) *(float4*)(ssc + j) = *(const float4*)(sb + j);
  __syncthreads();
  float si = ssc[i];
  int cnt = 0;
#pragma unroll
  for (int it = 0; it < N / 256; ++it) {
    int j = it * 256 + lane * 4;
    float4 v = *(const float4*)(ssc + j);
    cnt += (v.x > si) || (v.x == si && (j + 0) < i);
    cnt += (v.y > si) || (v.y == si && (j + 1) < i);
    cnt += (v.z > si) || (v.z == si && (j + 2) < i);
    cnt += (v.w > si) || (v.w == si && (j + 3) < i);
  }
#pragma unroll
  for (int m = 1; m < 64; m <<= 1) cnt += __shfl_xor(cnt, m, 64);
  if (lane == 0) {
    rank[b * N + i] = (cnt < CL) ? cnt : -1;
    if (cnt < CL) index_down[b * CL + cnt] = i;
  }
}

// ---------------- assignment: chunked center rows + packed atomicMin ----------------
__global__ __launch_bounds__(256) void k_assign_part(const float* __restrict__ distbuf,
                                                     const int* __restrict__ index_down,
                                                     unsigned long long* __restrict__ packed, int b0) {
  constexpr int RCH = CL / 8;  // 96
  __shared__ int sid[RCH];
  int bl = blockIdx.z, b = b0 + bl;
  int r0 = blockIdx.y * RCH;
  int tid = threadIdx.x;
  for (int r = tid; r < RCH; r += 256) sid[r] = index_down[b * CL + r0 + r];
  __syncthreads();
  int j = blockIdx.x * 256 + tid;
  const float* base = distbuf + (size_t)bl * N * N;
  float best = FLT_MAX; int bestr = 0;
#pragma unroll 8
  for (int r = 0; r < RCH; ++r) {
    float d = base[(size_t)sid[r] * N + j];
    if (d < best) { best = d; bestr = r0 + r; }
  }
  unsigned long long key = ((unsigned long long)__float_as_uint(best) << 32) | (unsigned)bestr;
  atomicMin(&packed[b * N + j], key);
}

__global__ void k_assign_fin2(const unsigned long long* __restrict__ packed,
                              const int* __restrict__ rank,
                              int* __restrict__ idx_cluster, int* __restrict__ counts) {
  int g = blockIdx.x * 256 + threadIdx.x;
  int b = g / N;
  int r = rank[g];
  int cl = (r >= 0) ? r : (int)(unsigned)(packed[g] & 0xffffffffull);
  idx_cluster[g] = cl;
  atomicAdd(&counts[b * CL + cl], 1);
}

// ---------------- merge ----------------
__global__ __launch_bounds__(1024) void k_scan(const int* __restrict__ counts,
                                               int* __restrict__ offsets, int* __restrict__ cursor) {
  constexpr int T = B * CL;
  __shared__ int sm[T];
  int tid = threadIdx.x;
  for (int p = tid; p < T; p += 1024) sm[p] = counts[p];
  __syncthreads();
  for (int off = 1; off < T; off <<= 1) {
    int v[3]; int n = 0;
    for (int p = tid; p < T; p += 1024) { v[n++] = (p >= off) ? sm[p - off] : 0; }
    __syncthreads();
    n = 0;
    for (int p = tid; p < T; p += 1024) { sm[p] += v[n++]; }
    __syncthreads();
  }
  for (int p = tid; p < T; p += 1024) {
    int e = sm[p] - counts[p];
    offsets[p] = e; cursor[p] = e;
  }
}

__global__ void k_fill(const int* __restrict__ idx_cluster, int* __restrict__ cursor,
                       int* __restrict__ members) {
  int g = blockIdx.x * 256 + threadIdx.x;
  int b = g / N, i = g % N;
  int seg = b * CL + idx_cluster[g];
  int pos = atomicAdd(&cursor[seg], 1);
  members[pos] = i;
}

__global__ __launch_bounds__(128) void k_gather(const float* __restrict__ x, const int* __restrict__ members,
                                                const int* __restrict__ offsets, const int* __restrict__ counts,
                                                float* __restrict__ out0) {
  int seg = blockIdx.x;
  int b = seg / CL;
  int cnt = counts[seg], off = offsets[seg];
  float nw = 1.0f / ((float)cnt + 1e-6f);
  int c = threadIdx.x * 4;
  const float* xb = x + (size_t)b * N * C;
  float4 acc = make_float4(0.f, 0.f, 0.f, 0.f);
  for (int m = 0; m < cnt; ++m) {
    int tok = members[off + m];
    float4 v = *(const float4*)(xb + (size_t)tok * C + c);
    acc.x += v.x * nw; acc.y += v.y * nw; acc.z += v.z * nw; acc.w += v.w * nw;
  }
  *(float4*)(out0 + (size_t)seg * C + c) = acc;
}

__global__ void k_final(const float* __restrict__ agg_weight, const int* __restrict__ idx_token,
                        const int* __restrict__ idx_cluster, const int* __restrict__ counts,
                        float* __restrict__ out1, float* __restrict__ out2, float* __restrict__ out3) {
  int g = blockIdx.x * 256 + threadIdx.x;
  int b = g / N;
  int it = idx_token[g];
  int clt = idx_cluster[b * N + it];
  float nwt = 1.0f / ((float)counts[b * CL + clt] + 1e-6f);
  out1[g] = agg_weight[g] * nwt;
  out2[g] = (float)clt;
  out3[g] = (float)idx_cluster[g];
}

// ---------------- launch ----------------
extern "C" void kernel_launch(void* const* d_in, const int* in_sizes, int n_in,
                              void* d_out, int out_size, void* d_ws, size_t ws_size,
                              hipStream_t stream) {
  const float* x          = (const float*)d_in[0];
  const int*   idx_token  = (const int*)d_in[1];
  const float* agg_weight = (const float*)d_in[2];

  float* out0 = (float*)d_out;
  float* out1 = out0 + (size_t)B * CL * C;
  float* out2 = out1 + (size_t)B * N;
  float* out3 = out2 + (size_t)B * N;

  char* w = (char*)d_ws;
  auto carve = [&](size_t bytes) { char* p = w; w += (bytes + 255) & ~(size_t)255; return p; };
  float*    sq         = (float*)carve((size_t)B * N * 4);
  float*    density    = (float*)carve((size_t)B * N * 4);
  float*    score      = (float*)carve((size_t)B * N * 4);
  float*    rowmax     = (float*)carve((size_t)B * N * 4);
  float*    distmax    = (float*)carve((size_t)B * 4);
  int*      index_down = (int*)carve((size_t)B * CL * 4);
  int*      rank       = (int*)carve((size_t)B * N * 4);
  int*      idx_clus   = (int*)carve((size_t)B * N * 4);
  int*      counts     = (int*)carve((size_t)B * CL * 4);
  int*      offsets    = (int*)carve((size_t)B * CL * 4);
  int*      cursor     = (int*)carve((size_t)B * CL * 4);
  int*      members    = (int*)carve((size_t)B * N * 4);
  unsigned long long* packed = (unsigned long long*)carve((size_t)B * N * 8);
  u16*      xhi        = (u16*)carve((size_t)B * N * C * 2);
  u16*      xlo        = (u16*)carve((size_t)B * N * C * 2);
  float*    part5      = (float*)carve((size_t)B * 48 * 6 * N * 4);
  size_t used = (size_t)(w - (char*)d_ws);
  size_t per  = (size_t)N * N * 4;
  int nb_max = (ws_size > used) ? (int)((ws_size - used) / per) : 0;
  if (nb_max < 1) nb_max = 1;
  if (nb_max > B) nb_max = B;
  float* distbuf = (float*)w;

  k_prep<<<B * N, 64, 0, stream>>>(x, sq, xhi, xlo, counts, packed);

  for (int b0 = 0; b0 < B; b0 += nb_max) {
    int nb = (B - b0 < nb_max) ? (B - b0) : nb_max;
    k_distm<<<dim3(NTILE3, nb), 256, 0, stream>>>(xhi, xlo, sq, distbuf, part5, b0);
    k_dens<<<(nb * N) / 256, 256, 0, stream>>>(part5, density, rowmax, b0);
    k_dmax<<<nb, 1024, 0, stream>>>(rowmax + (size_t)b0 * N, distmax + b0);
    k_maskmin<<<dim3(N / 4, nb), 256, 0, stream>>>(distbuf, density, distmax, score, b0);
    k_rank<<<dim3(N / 4, nb), 256, 0, stream>>>(score, index_down, rank, b0);
    k_assign_part<<<dim3(N / 256, 8, nb), 256, 0, stream>>>(distbuf, index_down, packed, b0);
  }

  k_assign_fin2<<<(B * N) / 256, 256, 0, stream>>>(packed, rank, idx_clus, counts);
  k_scan<<<1, 1024, 0, stream>>>(counts, offsets, cursor);
  k_fill<<<(B * N) / 256, 256, 0, stream>>>(idx_clus, cursor, members);
  k_gather<<<B * CL, 128, 0, stream>>>(x, members, offsets, counts, out0);
  k_final<<<(B * N) / 256, 256, 0, stream>>>(agg_weight, idx_token, idx_clus, counts, out1, out2, out3);
}